// Round 2
// baseline (1051.622 us; speedup 1.0000x reference)
//
#include <hip/hip_runtime.h>
#include <hip/hip_bf16.h>

#define NN 384
#define CC 128
#define HH 4
#define DHD 32
#define RR (NN*NN)
#define LN_EPS 1e-5f
#define SM_SCALE 0.17677669529663687f  // 1/sqrt(32)

typedef unsigned short u16;
typedef __bf16 bf16x8 __attribute__((ext_vector_type(8)));
typedef float f32x4 __attribute__((ext_vector_type(4)));
typedef unsigned short u16x8 __attribute__((ext_vector_type(8)));

__device__ __forceinline__ u16 f2bf(float f) {
    unsigned u = __float_as_uint(f);
    u += 0x7fffu + ((u >> 16) & 1u);        // RNE
    return (u16)(u >> 16);
}
__device__ __forceinline__ float bf2f(u16 s) { return __uint_as_float(((unsigned)s) << 16); }

// ---------------------------------------------------------------------------
// Kernel A: LayerNorm + q/k/v/gate projections + pair bias + w_o bf16 convert
// grid 2304, block 256. Each block: 64 rows (one b, rows m0..m0+64).
// ---------------------------------------------------------------------------
__global__ __launch_bounds__(256) void kernA(
    const float* __restrict__ pair, const float* __restrict__ ln_w, const float* __restrict__ ln_b,
    const float* __restrict__ w_bias, const float* __restrict__ w_q, const float* __restrict__ w_k,
    const float* __restrict__ w_v, const float* __restrict__ w_g, const float* __restrict__ w_o,
    u16* __restrict__ qbuf, u16* __restrict__ kbuf, u16* __restrict__ vT, u16* __restrict__ gbuf,
    float* __restrict__ biasf, u16* __restrict__ wob)
{
    __shared__ __align__(16) u16 x_tile[64*128];   // bf16, pitch 256B, XOR-swizzled
    __shared__ __align__(16) u16 w_lds[128*128];   // bf16, pitch 256B, XOR-swizzled

    const int t = threadIdx.x;
    const int bid = blockIdx.x;
    const int base = bid * 64;       // global row base (rows never cross a b: 384%64==0)
    const int b = base / NN;
    const int m0 = base % NN;

    if (bid == 0) {                   // one block converts w_o to bf16
        for (int i = t; i < CC*CC; i += 256) wob[i] = f2bf(w_o[i]);
    }

    // ---- LayerNorm: 4 lanes per row ----
    const int rl = t >> 2;
    const int lq = t & 3;
    const int grow = base + rl;
    float x[32];
    {
        const float* src = pair + (size_t)grow * CC + lq * 32;
        #pragma unroll
        for (int j = 0; j < 8; j++) {
            f32x4 v = *reinterpret_cast<const f32x4*>(src + j*4);
            #pragma unroll
            for (int e = 0; e < 4; e++) x[j*4+e] = v[e];
        }
    }
    float s = 0.f, sq = 0.f;
    #pragma unroll
    for (int j = 0; j < 32; j++) { s += x[j]; sq += x[j]*x[j]; }
    s  += __shfl_xor(s, 1);  s  += __shfl_xor(s, 2);
    sq += __shfl_xor(sq, 1); sq += __shfl_xor(sq, 2);
    const float mu = s * (1.f/128.f);
    const float rstd = rsqrtf(sq * (1.f/128.f) - mu*mu + LN_EPS);
    float pb[4] = {0.f,0.f,0.f,0.f};
    #pragma unroll
    for (int j = 0; j < 32; j++) {
        const int c = lq*32 + j;
        float xh = (x[j] - mu) * rstd * ln_w[c] + ln_b[c];
        x[j] = xh;
        #pragma unroll
        for (int h = 0; h < 4; h++) pb[h] += xh * w_bias[h*CC + c];
    }
    // write x (bf16) into swizzled LDS tile
    #pragma unroll
    for (int j8 = 0; j8 < 4; j8++) {
        u16x8 pk;
        #pragma unroll
        for (int e = 0; e < 8; e++) pk[e] = f2bf(x[j8*8 + e]);
        unsigned addr = (unsigned)(rl*256 + (lq*32 + j8*8)*2) ^ (unsigned)((rl & 7) << 4);
        *reinterpret_cast<u16x8*>(reinterpret_cast<char*>(x_tile) + addr) = pk;
    }
    // pair bias: bias[h][b'][n'] = dot(xhat, w_bias[h])
    #pragma unroll
    for (int h = 0; h < 4; h++) {
        float v = pb[h];
        v += __shfl_xor(v, 1); v += __shfl_xor(v, 2);
        if (lq == h) biasf[h*RR + grow] = v;
    }

    const int wv = t >> 6;
    const int lane = t & 63;
    const int lc = lane & 15;
    const int kg = lane >> 4;

    // A-frags for this wave's 16 rows (reused across all 4 weights)
    bf16x8 afr[4];
    {
        const int rA = wv*16 + lc;
        #pragma unroll
        for (int kt = 0; kt < 4; kt++) {
            unsigned addr = (unsigned)(rA*256 + (kt*32 + kg*8)*2) ^ (unsigned)((rA & 7) << 4);
            afr[kt] = *reinterpret_cast<const bf16x8*>(reinterpret_cast<const char*>(x_tile) + addr);
        }
    }

    const float* Ws[4] = {w_q, w_k, w_v, w_g};
    for (int wi = 0; wi < 4; wi++) {
        __syncthreads();                       // protect w_lds reuse
        const float* W = Ws[wi];
        #pragma unroll
        for (int i = 0; i < 8; i++) {
            const int chunk = i*256 + t;       // 2048 chunks of 8 elems
            const int row = chunk >> 4;
            const int colc = (chunk & 15) * 8;
            f32x4 v0 = *reinterpret_cast<const f32x4*>(W + row*CC + colc);
            f32x4 v1 = *reinterpret_cast<const f32x4*>(W + row*CC + colc + 4);
            u16x8 pk;
            #pragma unroll
            for (int e = 0; e < 4; e++) { pk[e] = f2bf(v0[e]); pk[4+e] = f2bf(v1[e]); }
            unsigned addr = (unsigned)(row*256 + colc*2) ^ (unsigned)((row & 7) << 4);
            *reinterpret_cast<u16x8*>(reinterpret_cast<char*>(w_lds) + addr) = pk;
        }
        __syncthreads();

        #pragma unroll
        for (int dt = 0; dt < 8; dt++) {
            f32x4 acc = {0.f, 0.f, 0.f, 0.f};
            const int rB = dt*16 + lc;
            #pragma unroll
            for (int kt = 0; kt < 4; kt++) {
                unsigned addr = (unsigned)(rB*256 + (kt*32 + kg*8)*2) ^ (unsigned)((rB & 7) << 4);
                bf16x8 bfr = *reinterpret_cast<const bf16x8*>(reinterpret_cast<const char*>(w_lds) + addr);
                acc = __builtin_amdgcn_mfma_f32_16x16x32_bf16(afr[kt], bfr, acc, 0, 0, 0);
            }
            if (wi == 2) {
                // v stored transposed: vT[b][d][m]
                #pragma unroll
                for (int i = 0; i < 4; i++) {
                    const int m = m0 + wv*16 + kg*4 + i;
                    vT[(size_t)(b*CC + dt*16 + lc) * NN + m] = f2bf(acc[i]);
                }
            } else {
                u16* dst = (wi == 0) ? qbuf : (wi == 1) ? kbuf : gbuf;
                #pragma unroll
                for (int i = 0; i < 4; i++) {
                    float v = acc[i];
                    if (wi == 3) v = 1.f / (1.f + __expf(-v));   // sigmoid gate
                    dst[(size_t)(base + wv*16 + kg*4 + i) * CC + dt*16 + lc] = f2bf(v);
                }
            }
        }
    }
}

// ---------------------------------------------------------------------------
// Kernel B: attention (S in registers, softmax in registers) + gate + out-proj
// grid 2304 = 384 b x 6 qtiles(64), block 256 (4 waves; wave = 16 queries)
// ---------------------------------------------------------------------------
__global__ __launch_bounds__(256) void kernB(
    const u16* __restrict__ qbuf, const u16* __restrict__ kbuf, const u16* __restrict__ vT,
    const u16* __restrict__ gbuf, const float* __restrict__ biasf, const u16* __restrict__ wob,
    const int* __restrict__ mask, float* __restrict__ out)
{
    __shared__ __align__(16) u16 P_lds[64*384];    // pitch 768B, swizzled; later aliased by gated-wa (pitch 256B)
    __shared__ __align__(16) float wa_lds[64*128]; // f32, pitch 512B, linear

    const int t = threadIdx.x;
    const int wv = t >> 6;
    const int lane = t & 63;
    const int lc = lane & 15;
    const int kg = lane >> 4;
    const int bid = blockIdx.x;
    const int b = bid / 6;
    const int q0 = (bid % 6) * 64;
    const int qt = q0 + wv*16;       // this wave's query tile base (within b)

    // mask bias per lane per m-tile (mask: [b, key], int32 on device)
    float mbias[24];
    #pragma unroll
    for (int mt = 0; mt < 24; mt++)
        mbias[mt] = (mask[b*NN + mt*16 + lc] != 0) ? 0.f : -1e9f;

    for (int h = 0; h < HH; h++) {
        const bf16x8 aq = *reinterpret_cast<const bf16x8*>(
            qbuf + (size_t)(b*NN + qt + lc)*CC + h*DHD + kg*8);

        // S = q.k^T  (K = Dh = 32 -> single MFMA per 16x16 tile)
        f32x4 S[24];
        #pragma unroll
        for (int mt = 0; mt < 24; mt++) {
            const bf16x8 bk = *reinterpret_cast<const bf16x8*>(
                kbuf + (size_t)(b*NN + mt*16 + lc)*CC + h*DHD + kg*8);
            f32x4 z = {0.f,0.f,0.f,0.f};
            S[mt] = __builtin_amdgcn_mfma_f32_16x16x32_bf16(aq, bk, z, 0, 0, 0);
        }
        // scale + pair bias + mask, track row max
        float mx[4] = {-3e38f,-3e38f,-3e38f,-3e38f};
        #pragma unroll
        for (int mt = 0; mt < 24; mt++) {
            const int m = mt*16 + lc;
            const float* bp = biasf + (size_t)h*RR + (size_t)(qt + kg*4)*NN + m;
            #pragma unroll
            for (int i = 0; i < 4; i++) {
                float v = S[mt][i] * SM_SCALE + bp[(size_t)i*NN] + mbias[mt];
                S[mt][i] = v;
                mx[i] = fmaxf(mx[i], v);
            }
        }
        #pragma unroll
        for (int i = 0; i < 4; i++) {
            mx[i] = fmaxf(mx[i], __shfl_xor(mx[i], 1));
            mx[i] = fmaxf(mx[i], __shfl_xor(mx[i], 2));
            mx[i] = fmaxf(mx[i], __shfl_xor(mx[i], 4));
            mx[i] = fmaxf(mx[i], __shfl_xor(mx[i], 8));
        }
        float sm[4] = {0.f,0.f,0.f,0.f};
        #pragma unroll
        for (int mt = 0; mt < 24; mt++) {
            #pragma unroll
            for (int i = 0; i < 4; i++) {
                float e = __expf(S[mt][i] - mx[i]);
                S[mt][i] = e;
                sm[i] += e;
            }
        }
        #pragma unroll
        for (int i = 0; i < 4; i++) {
            sm[i] += __shfl_xor(sm[i], 1);
            sm[i] += __shfl_xor(sm[i], 2);
            sm[i] += __shfl_xor(sm[i], 4);
            sm[i] += __shfl_xor(sm[i], 8);
            sm[i] = 1.f / sm[i];
        }
        // normalized P -> bf16 -> swizzled LDS (wave-private rows)
        #pragma unroll
        for (int mt = 0; mt < 24; mt++) {
            #pragma unroll
            for (int i = 0; i < 4; i++) {
                const int rloc = wv*16 + kg*4 + i;
                unsigned addr = (unsigned)(rloc*768 + (mt*16 + lc)*2) ^ (unsigned)((rloc & 7) << 4);
                *reinterpret_cast<u16*>(reinterpret_cast<char*>(P_lds) + addr) = f2bf(S[mt][i] * sm[i]);
            }
        }
        // PV: wa[q][d] = P . v   (A from LDS, B from vT global - contiguous)
        bf16x8 ap[12];
        {
            const int rloc = wv*16 + lc;
            #pragma unroll
            for (int kt = 0; kt < 12; kt++) {
                unsigned addr = (unsigned)(rloc*768 + (kt*32 + kg*8)*2) ^ (unsigned)((rloc & 7) << 4);
                ap[kt] = *reinterpret_cast<const bf16x8*>(reinterpret_cast<const char*>(P_lds) + addr);
            }
        }
        #pragma unroll
        for (int dt = 0; dt < 2; dt++) {
            f32x4 acc = {0.f,0.f,0.f,0.f};
            #pragma unroll
            for (int kt = 0; kt < 12; kt++) {
                const bf16x8 bv = *reinterpret_cast<const bf16x8*>(
                    vT + (size_t)(b*CC + h*DHD + dt*16 + lc)*NN + kt*32 + kg*8);
                acc = __builtin_amdgcn_mfma_f32_16x16x32_bf16(ap[kt], bv, acc, 0, 0, 0);
            }
            #pragma unroll
            for (int i = 0; i < 4; i++)
                wa_lds[(wv*16 + kg*4 + i)*CC + h*DHD + dt*16 + lc] = acc[i];
        }
    }

    __syncthreads();   // wag (below) aliases P_lds across wave regions

    // gating: wag = wa * sigmoid-gate, bf16, swizzled into P_lds alias
    {
        const int rl = t >> 2;
        const int lq = t & 3;
        const u16* g = gbuf + (size_t)(b*NN + q0 + rl)*CC + lq*32;
        #pragma unroll
        for (int j8 = 0; j8 < 4; j8++) {
            u16x8 gv = *reinterpret_cast<const u16x8*>(g + j8*8);
            u16x8 pk;
            #pragma unroll
            for (int e = 0; e < 8; e++) {
                float wa = wa_lds[rl*CC + lq*32 + j8*8 + e];
                pk[e] = f2bf(wa * bf2f(gv[e]));
            }
            unsigned addr = (unsigned)(rl*256 + (lq*32 + j8*8)*2) ^ (unsigned)((rl & 7) << 4);
            *reinterpret_cast<u16x8*>(reinterpret_cast<char*>(P_lds) + addr) = pk;
        }
    }
    __syncthreads();

    // out projection: out = wag . w_o^T
    {
        bf16x8 afr[4];
        const int rloc = wv*16 + lc;
        #pragma unroll
        for (int kt = 0; kt < 4; kt++) {
            unsigned addr = (unsigned)(rloc*256 + (kt*32 + kg*8)*2) ^ (unsigned)((rloc & 7) << 4);
            afr[kt] = *reinterpret_cast<const bf16x8*>(reinterpret_cast<const char*>(P_lds) + addr);
        }
        #pragma unroll
        for (int et = 0; et < 8; et++) {
            f32x4 acc = {0.f,0.f,0.f,0.f};
            #pragma unroll
            for (int kt = 0; kt < 4; kt++) {
                const bf16x8 bw = *reinterpret_cast<const bf16x8*>(wob + (et*16 + lc)*CC + kt*32 + kg*8);
                acc = __builtin_amdgcn_mfma_f32_16x16x32_bf16(afr[kt], bw, acc, 0, 0, 0);
            }
            #pragma unroll
            for (int i = 0; i < 4; i++)
                out[(size_t)(b*NN + q0 + wv*16 + kg*4 + i)*CC + et*16 + lc] = acc[i];
        }
    }
}

extern "C" void kernel_launch(void* const* d_in, const int* in_sizes, int n_in,
                              void* d_out, int out_size, void* d_ws, size_t ws_size,
                              hipStream_t stream)
{
    const float* pair  = (const float*)d_in[0];
    const int*   mask  = (const int*)d_in[1];
    const float* ln_w  = (const float*)d_in[2];
    const float* ln_b  = (const float*)d_in[3];
    const float* w_bias= (const float*)d_in[4];
    const float* w_q   = (const float*)d_in[5];
    const float* w_k   = (const float*)d_in[6];
    const float* w_v   = (const float*)d_in[7];
    const float* w_g   = (const float*)d_in[8];
    const float* w_o   = (const float*)d_in[9];
    float* out = (float*)d_out;

    // workspace layout
    char* ws = (char*)d_ws;
    const size_t SZ = (size_t)RR * CC * 2;       // 37,748,736 bytes each
    u16* qbuf = (u16*)(ws);
    u16* kbuf = (u16*)(ws + SZ);
    u16* vT   = (u16*)(ws + 2*SZ);
    u16* gbuf = (u16*)(ws + 3*SZ);
    float* biasf = (float*)(ws + 4*SZ);          // 4*RR*4 = 2,359,296 bytes
    u16* wob  = (u16*)(ws + 4*SZ + (size_t)4*RR*4);  // 32 KiB

    kernA<<<dim3(RR/64), dim3(256), 0, stream>>>(pair, ln_w, ln_b, w_bias,
        w_q, w_k, w_v, w_g, w_o, qbuf, kbuf, vT, gbuf, biasf, wob);
    kernB<<<dim3(NN*6), dim3(256), 0, stream>>>(qbuf, kbuf, vT, gbuf, biasf, wob, mask, out);
}

// Round 3
// 989.635 us; speedup vs baseline: 1.0626x; 1.0626x over previous
//
#include <hip/hip_runtime.h>
#include <hip/hip_bf16.h>

#define NN 384
#define CC 128
#define HH 4
#define DHD 32
#define RR (NN*NN)
#define LN_EPS 1e-5f
#define SM_SCALE 0.17677669529663687f  // 1/sqrt(32)
#define NBB (NN*24)                     // kernB grid: 9216

typedef unsigned short u16;
typedef __bf16 bf16x8 __attribute__((ext_vector_type(8)));
typedef float f32x4 __attribute__((ext_vector_type(4)));
typedef unsigned short u16x8 __attribute__((ext_vector_type(8)));

__device__ __forceinline__ u16 f2bf(float f) {
    unsigned u = __float_as_uint(f);
    u += 0x7fffu + ((u >> 16) & 1u);        // RNE
    return (u16)(u >> 16);
}
__device__ __forceinline__ float bf2f(u16 s) { return __uint_as_float(((unsigned)s) << 16); }

// ---------------------------------------------------------------------------
// Kernel A: LayerNorm + q/k/v/gate projections + pair bias + w_o bf16 convert
// grid 2304, block 256. Each block: 64 rows (one b, rows m0..m0+64).
// ---------------------------------------------------------------------------
__global__ __launch_bounds__(256) void kernA(
    const float* __restrict__ pair, const float* __restrict__ ln_w, const float* __restrict__ ln_b,
    const float* __restrict__ w_bias, const float* __restrict__ w_q, const float* __restrict__ w_k,
    const float* __restrict__ w_v, const float* __restrict__ w_g, const float* __restrict__ w_o,
    u16* __restrict__ qbuf, u16* __restrict__ kbuf, u16* __restrict__ vT, u16* __restrict__ gbuf,
    float* __restrict__ biasf, u16* __restrict__ wob)
{
    __shared__ __align__(16) u16 x_tile[64*128];   // bf16, pitch 256B, XOR-swizzled
    __shared__ __align__(16) u16 w_lds[128*128];   // bf16, pitch 256B, XOR-swizzled

    const int t = threadIdx.x;
    const int bid = blockIdx.x;
    const int base = bid * 64;       // global row base (rows never cross a b: 384%64==0)
    const int b = base / NN;
    const int m0 = base % NN;

    if (bid == 0) {                   // one block converts w_o to bf16
        for (int i = t; i < CC*CC; i += 256) wob[i] = f2bf(w_o[i]);
    }

    // ---- LayerNorm: 4 lanes per row ----
    const int rl = t >> 2;
    const int lq = t & 3;
    const int grow = base + rl;
    float x[32];
    {
        const float* src = pair + (size_t)grow * CC + lq * 32;
        #pragma unroll
        for (int j = 0; j < 8; j++) {
            f32x4 v = *reinterpret_cast<const f32x4*>(src + j*4);
            #pragma unroll
            for (int e = 0; e < 4; e++) x[j*4+e] = v[e];
        }
    }
    float s = 0.f, sq = 0.f;
    #pragma unroll
    for (int j = 0; j < 32; j++) { s += x[j]; sq += x[j]*x[j]; }
    s  += __shfl_xor(s, 1);  s  += __shfl_xor(s, 2);
    sq += __shfl_xor(sq, 1); sq += __shfl_xor(sq, 2);
    const float mu = s * (1.f/128.f);
    const float rstd = rsqrtf(sq * (1.f/128.f) - mu*mu + LN_EPS);
    float pb[4] = {0.f,0.f,0.f,0.f};
    #pragma unroll
    for (int j = 0; j < 32; j++) {
        const int c = lq*32 + j;
        float xh = (x[j] - mu) * rstd * ln_w[c] + ln_b[c];
        x[j] = xh;
        #pragma unroll
        for (int h = 0; h < 4; h++) pb[h] += xh * w_bias[h*CC + c];
    }
    // write x (bf16) into swizzled LDS tile
    #pragma unroll
    for (int j8 = 0; j8 < 4; j8++) {
        u16x8 pk;
        #pragma unroll
        for (int e = 0; e < 8; e++) pk[e] = f2bf(x[j8*8 + e]);
        unsigned addr = (unsigned)(rl*256 + (lq*32 + j8*8)*2) ^ (unsigned)((rl & 7) << 4);
        *reinterpret_cast<u16x8*>(reinterpret_cast<char*>(x_tile) + addr) = pk;
    }
    // pair bias: bias[h][q][k] = dot(xhat, w_bias[h])
    #pragma unroll
    for (int h = 0; h < 4; h++) {
        float v = pb[h];
        v += __shfl_xor(v, 1); v += __shfl_xor(v, 2);
        if (lq == h) biasf[h*RR + grow] = v;
    }

    const int wv = t >> 6;
    const int lane = t & 63;
    const int lc = lane & 15;
    const int kg = lane >> 4;

    // A-frags for this wave's 16 rows (reused across all 4 weights)
    bf16x8 afr[4];
    {
        const int rA = wv*16 + lc;
        #pragma unroll
        for (int kt = 0; kt < 4; kt++) {
            unsigned addr = (unsigned)(rA*256 + (kt*32 + kg*8)*2) ^ (unsigned)((rA & 7) << 4);
            afr[kt] = *reinterpret_cast<const bf16x8*>(reinterpret_cast<const char*>(x_tile) + addr);
        }
    }

    const float* Ws[4] = {w_q, w_k, w_v, w_g};
    for (int wi = 0; wi < 4; wi++) {
        __syncthreads();                       // protect w_lds reuse
        const float* W = Ws[wi];
        #pragma unroll
        for (int i = 0; i < 8; i++) {
            const int chunk = i*256 + t;       // 2048 chunks of 8 elems
            const int row = chunk >> 4;
            const int colc = (chunk & 15) * 8;
            f32x4 v0 = *reinterpret_cast<const f32x4*>(W + row*CC + colc);
            f32x4 v1 = *reinterpret_cast<const f32x4*>(W + row*CC + colc + 4);
            u16x8 pk;
            #pragma unroll
            for (int e = 0; e < 4; e++) { pk[e] = f2bf(v0[e]); pk[4+e] = f2bf(v1[e]); }
            unsigned addr = (unsigned)(row*256 + colc*2) ^ (unsigned)((row & 7) << 4);
            *reinterpret_cast<u16x8*>(reinterpret_cast<char*>(w_lds) + addr) = pk;
        }
        __syncthreads();

        #pragma unroll
        for (int dt = 0; dt < 8; dt++) {
            f32x4 acc = {0.f, 0.f, 0.f, 0.f};
            const int rB = dt*16 + lc;
            #pragma unroll
            for (int kt = 0; kt < 4; kt++) {
                unsigned addr = (unsigned)(rB*256 + (kt*32 + kg*8)*2) ^ (unsigned)((rB & 7) << 4);
                bf16x8 bfr = *reinterpret_cast<const bf16x8*>(reinterpret_cast<const char*>(w_lds) + addr);
                acc = __builtin_amdgcn_mfma_f32_16x16x32_bf16(afr[kt], bfr, acc, 0, 0, 0);
            }
            if (wi == 2) {
                // v stored transposed: vT[b][d][m]
                #pragma unroll
                for (int i = 0; i < 4; i++) {
                    const int m = m0 + wv*16 + kg*4 + i;
                    vT[(size_t)(b*CC + dt*16 + lc) * NN + m] = f2bf(acc[i]);
                }
            } else {
                u16* dst = (wi == 0) ? qbuf : (wi == 1) ? kbuf : gbuf;
                #pragma unroll
                for (int i = 0; i < 4; i++) {
                    float v = acc[i];
                    if (wi == 3) v = 1.f / (1.f + __expf(-v));   // sigmoid gate
                    dst[(size_t)(base + wv*16 + kg*4 + i) * CC + dt*16 + lc] = f2bf(v);
                }
            }
        }
    }
}

// ---------------------------------------------------------------------------
// Kernel B: attention only. 1 wave per block, 16 queries, all 4 heads.
// grid 9216 = 384 b x 24 qtiles. No barriers; LDS = wave-private P (12 KB).
// Writes gated wa (bf16) into wagbuf.
// ---------------------------------------------------------------------------
__global__ __launch_bounds__(64, 3) void kernB(
    const u16* __restrict__ qbuf, const u16* __restrict__ kbuf, const u16* __restrict__ vT,
    const u16* __restrict__ gbuf, const float* __restrict__ biasf,
    const int* __restrict__ mask, u16* __restrict__ wagbuf)
{
    __shared__ __align__(16) u16 P_lds[16*384];   // pitch 768B, XOR-swizzled

    const int t = threadIdx.x;
    const int lc = t & 15;
    const int kg = t >> 4;
    int bid = blockIdx.x;
    bid = (bid & 7) * (NBB/8) + (bid >> 3);   // XCD-aware swizzle (bijective: 9216%8==0)
    const int b = bid / 24;
    const int qt = (bid % 24) * 16;

    // mask bits (key-mask per lane's 24 m-tiles), 1 VGPR
    unsigned mbits = 0u;
    #pragma unroll
    for (int mt = 0; mt < 24; mt++)
        mbits |= (mask[b*NN + mt*16 + lc] != 0 ? 1u : 0u) << mt;

    for (int h = 0; h < HH; h++) {
        const bf16x8 aq = *reinterpret_cast<const bf16x8*>(
            qbuf + (size_t)(b*NN + qt + lc)*CC + h*DHD + kg*8);

        // S = q.k^T  (K = Dh = 32 -> single MFMA per 16x16 tile)
        f32x4 S[24];
        #pragma unroll
        for (int mt = 0; mt < 24; mt++) {
            const bf16x8 bk = *reinterpret_cast<const bf16x8*>(
                kbuf + (size_t)(b*NN + mt*16 + lc)*CC + h*DHD + kg*8);
            f32x4 z = {0.f,0.f,0.f,0.f};
            S[mt] = __builtin_amdgcn_mfma_f32_16x16x32_bf16(aq, bk, z, 0, 0, 0);
        }
        // scale + pair bias + mask, track row max
        float mx[4] = {-3e38f,-3e38f,-3e38f,-3e38f};
        #pragma unroll
        for (int mt = 0; mt < 24; mt++) {
            const float mb = ((mbits >> mt) & 1u) ? 0.f : -1e9f;
            const float* bp = biasf + (size_t)h*RR + (size_t)(qt + kg*4)*NN + mt*16 + lc;
            #pragma unroll
            for (int i = 0; i < 4; i++) {
                float v = S[mt][i] * SM_SCALE + bp[(size_t)i*NN] + mb;
                S[mt][i] = v;
                mx[i] = fmaxf(mx[i], v);
            }
        }
        #pragma unroll
        for (int i = 0; i < 4; i++) {
            mx[i] = fmaxf(mx[i], __shfl_xor(mx[i], 1));
            mx[i] = fmaxf(mx[i], __shfl_xor(mx[i], 2));
            mx[i] = fmaxf(mx[i], __shfl_xor(mx[i], 4));
            mx[i] = fmaxf(mx[i], __shfl_xor(mx[i], 8));
        }
        float sm[4] = {0.f,0.f,0.f,0.f};
        #pragma unroll
        for (int mt = 0; mt < 24; mt++) {
            #pragma unroll
            for (int i = 0; i < 4; i++) {
                float e = __expf(S[mt][i] - mx[i]);
                S[mt][i] = e;
                sm[i] += e;
            }
        }
        float sminv[4];
        #pragma unroll
        for (int i = 0; i < 4; i++) {
            sm[i] += __shfl_xor(sm[i], 1);
            sm[i] += __shfl_xor(sm[i], 2);
            sm[i] += __shfl_xor(sm[i], 4);
            sm[i] += __shfl_xor(sm[i], 8);
            sminv[i] = 1.f / sm[i];
        }
        // UNNORMALIZED P -> bf16 -> swizzled LDS (single wave: no barrier needed)
        #pragma unroll
        for (int mt = 0; mt < 24; mt++) {
            #pragma unroll
            for (int i = 0; i < 4; i++) {
                const int rloc = kg*4 + i;
                unsigned addr = (unsigned)(rloc*768 + (mt*16 + lc)*2) ^ (unsigned)((rloc & 7) << 4);
                *reinterpret_cast<u16*>(reinterpret_cast<char*>(P_lds) + addr) = f2bf(S[mt][i]);
            }
        }
        // PV: wa[q][d] = P . v   (A from LDS, B from vT global - contiguous)
        bf16x8 ap[12];
        {
            const int rloc = lc;
            #pragma unroll
            for (int kt = 0; kt < 12; kt++) {
                unsigned addr = (unsigned)(rloc*768 + (kt*32 + kg*8)*2) ^ (unsigned)((rloc & 7) << 4);
                ap[kt] = *reinterpret_cast<const bf16x8*>(reinterpret_cast<const char*>(P_lds) + addr);
            }
        }
        #pragma unroll
        for (int dt = 0; dt < 2; dt++) {
            f32x4 acc = {0.f,0.f,0.f,0.f};
            #pragma unroll
            for (int kt = 0; kt < 12; kt++) {
                const bf16x8 bv = *reinterpret_cast<const bf16x8*>(
                    vT + (size_t)(b*CC + h*DHD + dt*16 + lc)*NN + kt*32 + kg*8);
                acc = __builtin_amdgcn_mfma_f32_16x16x32_bf16(ap[kt], bv, acc, 0, 0, 0);
            }
            // normalize (deferred), gate, store gated wa
            #pragma unroll
            for (int i = 0; i < 4; i++) {
                const size_t row = (size_t)(b*NN + qt + kg*4 + i);
                const int col = h*DHD + dt*16 + lc;
                float g = bf2f(gbuf[row*CC + col]);
                wagbuf[row*CC + col] = f2bf(acc[i] * sminv[i] * g);
            }
        }
    }
}

// ---------------------------------------------------------------------------
// Kernel C: out = wag . w_o^T   (streaming GEMM, grid 2304 x 256)
// ---------------------------------------------------------------------------
__global__ __launch_bounds__(256) void kernC(
    const u16* __restrict__ wag, const u16* __restrict__ wob, float* __restrict__ out)
{
    __shared__ __align__(16) u16 a_tile[64*128];   // bf16, pitch 256B, XOR-swizzled

    const int t = threadIdx.x;
    const int base = blockIdx.x * 64;

    // stage 64 rows of wag into LDS
    {
        const int rl = t >> 2;
        const int lq = t & 3;
        const u16* src = wag + (size_t)(base + rl)*CC + lq*32;
        #pragma unroll
        for (int j8 = 0; j8 < 4; j8++) {
            u16x8 v = *reinterpret_cast<const u16x8*>(src + j8*8);
            unsigned addr = (unsigned)(rl*256 + (lq*32 + j8*8)*2) ^ (unsigned)((rl & 7) << 4);
            *reinterpret_cast<u16x8*>(reinterpret_cast<char*>(a_tile) + addr) = v;
        }
    }
    __syncthreads();

    const int wv = t >> 6;
    const int lane = t & 63;
    const int lc = lane & 15;
    const int kg = lane >> 4;

    bf16x8 afr[4];
    {
        const int rA = wv*16 + lc;
        #pragma unroll
        for (int kt = 0; kt < 4; kt++) {
            unsigned addr = (unsigned)(rA*256 + (kt*32 + kg*8)*2) ^ (unsigned)((rA & 7) << 4);
            afr[kt] = *reinterpret_cast<const bf16x8*>(reinterpret_cast<const char*>(a_tile) + addr);
        }
    }
    #pragma unroll
    for (int et = 0; et < 8; et++) {
        f32x4 acc = {0.f,0.f,0.f,0.f};
        #pragma unroll
        for (int kt = 0; kt < 4; kt++) {
            const bf16x8 bw = *reinterpret_cast<const bf16x8*>(wob + (et*16 + lc)*CC + kt*32 + kg*8);
            acc = __builtin_amdgcn_mfma_f32_16x16x32_bf16(afr[kt], bw, acc, 0, 0, 0);
        }
        #pragma unroll
        for (int i = 0; i < 4; i++)
            out[(size_t)(base + wv*16 + kg*4 + i)*CC + et*16 + lc] = acc[i];
    }
}

extern "C" void kernel_launch(void* const* d_in, const int* in_sizes, int n_in,
                              void* d_out, int out_size, void* d_ws, size_t ws_size,
                              hipStream_t stream)
{
    const float* pair  = (const float*)d_in[0];
    const int*   mask  = (const int*)d_in[1];
    const float* ln_w  = (const float*)d_in[2];
    const float* ln_b  = (const float*)d_in[3];
    const float* w_bias= (const float*)d_in[4];
    const float* w_q   = (const float*)d_in[5];
    const float* w_k   = (const float*)d_in[6];
    const float* w_v   = (const float*)d_in[7];
    const float* w_g   = (const float*)d_in[8];
    const float* w_o   = (const float*)d_in[9];
    float* out = (float*)d_out;

    // workspace layout
    char* ws = (char*)d_ws;
    const size_t SZ = (size_t)RR * CC * 2;       // 37,748,736 bytes each
    u16* qbuf = (u16*)(ws);
    u16* kbuf = (u16*)(ws + SZ);
    u16* vT   = (u16*)(ws + 2*SZ);
    u16* gbuf = (u16*)(ws + 3*SZ);
    float* biasf = (float*)(ws + 4*SZ);          // 4*RR*4 = 2,359,296 bytes
    u16* wob  = (u16*)(ws + 4*SZ + (size_t)4*RR*4);  // 32 KiB
    const size_t used = 4*SZ + (size_t)4*RR*4 + (size_t)CC*CC*2;
    // wag: separate buffer if workspace allows, else alias qbuf (in-place is
    // safe: each wave reads q[row, 32h..32h+32) before writing wag to the
    // exact same row/col range, and rows are owned by exactly one wave).
    u16* wagbuf = (ws_size >= used + SZ) ? (u16*)(ws + used) : qbuf;

    kernA<<<dim3(RR/64), dim3(256), 0, stream>>>(pair, ln_w, ln_b, w_bias,
        w_q, w_k, w_v, w_g, w_o, qbuf, kbuf, vT, gbuf, biasf, wob);
    kernB<<<dim3(NBB), dim3(64), 0, stream>>>(qbuf, kbuf, vT, gbuf, biasf, mask, wagbuf);
    kernC<<<dim3(RR/64), dim3(256), 0, stream>>>(wagbuf, wob, out);
}